// Round 6
// baseline (349.131 us; speedup 1.0000x reference)
//
#include <hip/hip_runtime.h>
#include <stdint.h>

typedef __attribute__((ext_vector_type(8))) short short8x;
typedef __attribute__((ext_vector_type(4))) float float4x;

#define B_SZ 4
#define T_SEQ 2048
#define HID_SZ 768
#define NH 12
#define HD 64
#define LDP 72  // padded LDS leading dim (elements): 144B rows, 16B aligned

__device__ __forceinline__ unsigned short f2b(float f) {
    union { float f; unsigned int u; } v; v.f = f;
    unsigned int u = v.u;
    u += 0x7fffu + ((u >> 16) & 1u);   // RNE
    return (unsigned short)(u >> 16);
}

// ---------------- QKV projection: Y = X @ W^T + b, output bf16 [B,H,T,D] ----
__global__ __launch_bounds__(256) void qkv_gemm(
    const float* __restrict__ X, const float* __restrict__ W,
    const float* __restrict__ bias, unsigned short* __restrict__ Y)
{
    __shared__ unsigned short As[128 * LDP];
    __shared__ unsigned short Bs[128 * LDP];
    const int tid  = threadIdx.x;
    const int lane = tid & 63;
    const int w    = tid >> 6;
    const int bm = blockIdx.x, bn = blockIdx.y;
    const int wm = (w >> 1) * 64, wn = (w & 1) * 64;
    const int lr = lane & 15;
    const int hi = lane >> 4;

    float4x acc[4][4];
#pragma unroll
    for (int i = 0; i < 4; ++i)
#pragma unroll
        for (int j = 0; j < 4; ++j) acc[i][j] = (float4x)0.0f;

    for (int k0 = 0; k0 < HID_SZ; k0 += 64) {
        __syncthreads();
#pragma unroll
        for (int i = 0; i < 8; ++i) {
            int f4 = tid + i * 256;          // 2048 float4 = 128 rows x 16
            int row = f4 >> 4, c4 = f4 & 15;
            float4 va = *(const float4*)(X + (size_t)(bm * 128 + row) * HID_SZ + k0 + c4 * 4);
            unsigned short* da = &As[row * LDP + c4 * 4];
            da[0] = f2b(va.x); da[1] = f2b(va.y); da[2] = f2b(va.z); da[3] = f2b(va.w);
            float4 vb = *(const float4*)(W + (size_t)(bn * 128 + row) * HID_SZ + k0 + c4 * 4);
            unsigned short* db = &Bs[row * LDP + c4 * 4];
            db[0] = f2b(vb.x); db[1] = f2b(vb.y); db[2] = f2b(vb.z); db[3] = f2b(vb.w);
        }
        __syncthreads();

        short8x a[4][2], bf[4][2];
#pragma unroll
        for (int rf = 0; rf < 4; ++rf)
#pragma unroll
            for (int ks = 0; ks < 2; ++ks)
                a[rf][ks] = *(const short8x*)&As[(wm + rf * 16 + lr) * LDP + ks * 32 + hi * 8];
#pragma unroll
        for (int cf = 0; cf < 4; ++cf)
#pragma unroll
            for (int ks = 0; ks < 2; ++ks)
                bf[cf][ks] = *(const short8x*)&Bs[(wn + cf * 16 + lr) * LDP + ks * 32 + hi * 8];
#pragma unroll
        for (int rf = 0; rf < 4; ++rf)
#pragma unroll
            for (int cf = 0; cf < 4; ++cf)
#pragma unroll
                for (int ks = 0; ks < 2; ++ks)
                    acc[rf][cf] = __builtin_amdgcn_mfma_f32_16x16x32_bf16(
                        a[rf][ks], bf[cf][ks], acc[rf][cf], 0, 0, 0);
    }

#pragma unroll
    for (int rf = 0; rf < 4; ++rf)
#pragma unroll
        for (int cf = 0; cf < 4; ++cf) {
            int n = bn * 128 + wn + cf * 16 + lr;
            float bv = bias[n];
            int h = n >> 6, d = n & 63;
#pragma unroll
            for (int reg = 0; reg < 4; ++reg) {
                int m = bm * 128 + wm + rf * 16 + hi * 4 + reg;
                int b = m >> 11, t = m & 2047;
                Y[(((size_t)b * NH + h) * T_SEQ + t) * HD + d] = f2b(acc[rf][cf][reg] + bv);
            }
        }
}

// ---------------- Flash attention: per (b,h), 128 q-rows per block ----------
__global__ __launch_bounds__(256) void attn(
    const unsigned short* __restrict__ Q, const unsigned short* __restrict__ K,
    const unsigned short* __restrict__ V, const float* __restrict__ mask,
    float* __restrict__ out)
{
    __shared__ unsigned short Qs[128 * LDP];
    __shared__ unsigned short Ks[64 * LDP];
    __shared__ unsigned short Vt[64 * LDP];      // transposed: Vt[d][key]
    __shared__ unsigned short Ps[4][32 * LDP];   // per-wave P buffer

    const int tid = threadIdx.x, lane = tid & 63, w = tid >> 6;
    const int lr = lane & 15, hi = lane >> 4;
    const int bx = blockIdx.x;            // q tile
    const int bh = blockIdx.y;            // b*NH + h
    const int b = bh / NH, h = bh % NH;
    const int q0 = bx * 128;
    const size_t base = (size_t)bh * T_SEQ * HD;

    // stage Q tile (bf16, padded rows)
#pragma unroll
    for (int i = 0; i < 4; ++i) {
        int f8 = tid + i * 256;           // 1024 short8 = 128 rows x 8
        int row = f8 >> 3, c8 = f8 & 7;
        short8x v = *(const short8x*)(Q + base + (size_t)(q0 + row) * HD + c8 * 8);
        *(short8x*)&Qs[row * LDP + c8 * 8] = v;
    }
    __syncthreads();

    // hoist Q fragments (loop-invariant)
    short8x qa[2][2];
#pragma unroll
    for (int rf = 0; rf < 2; ++rf)
#pragma unroll
        for (int ks = 0; ks < 2; ++ks)
            qa[rf][ks] = *(const short8x*)&Qs[(w * 32 + rf * 16 + lr) * LDP + ks * 32 + hi * 8];

    float4x o[2][4];
    float mrun[2][4], lrun[2][4];
#pragma unroll
    for (int rf = 0; rf < 2; ++rf)
#pragma unroll
        for (int j = 0; j < 4; ++j) {
            o[rf][j] = (float4x)0.0f;
            mrun[rf][j] = -3.0e38f;
            lrun[rf][j] = 0.0f;
        }

    const int nkv = 2 * bx + 2;
    for (int kv = 0; kv < nkv; ++kv) {
        __syncthreads();  // all waves done reading prev K/V tiles
#pragma unroll
        for (int i = 0; i < 2; ++i) {
            int f8 = tid + i * 256;       // 512 short8 = 64 rows x 8
            int row = f8 >> 3, c8 = f8 & 7;
            short8x kvv = *(const short8x*)(K + base + (size_t)(kv * 64 + row) * HD + c8 * 8);
            *(short8x*)&Ks[row * LDP + c8 * 8] = kvv;
            short8x vv = *(const short8x*)(V + base + (size_t)(kv * 64 + row) * HD + c8 * 8);
#pragma unroll
            for (int j = 0; j < 8; ++j)
                Vt[(c8 * 8 + j) * LDP + row] = (unsigned short)vv[j];
        }
        __syncthreads();

        // S = Q K^T  (per wave: 32 q-rows x 64 keys)
        short8x kb[4][2];
#pragma unroll
        for (int c = 0; c < 4; ++c)
#pragma unroll
            for (int ks = 0; ks < 2; ++ks)
                kb[c][ks] = *(const short8x*)&Ks[(c * 16 + lr) * LDP + ks * 32 + hi * 8];

        float4x s[2][4];
#pragma unroll
        for (int rf = 0; rf < 2; ++rf)
#pragma unroll
            for (int c = 0; c < 4; ++c) {
                s[rf][c] = (float4x)0.0f;
#pragma unroll
                for (int ks = 0; ks < 2; ++ks)
                    s[rf][c] = __builtin_amdgcn_mfma_f32_16x16x32_bf16(
                        qa[rf][ks], kb[c][ks], s[rf][c], 0, 0, 0);
            }

        // scale + additive mask + causal
        float mval[4];
#pragma unroll
        for (int c = 0; c < 4; ++c) mval[c] = mask[b * T_SEQ + kv * 64 + c * 16 + lr];
        const bool needMask = (kv * 64 + 63 > q0);
        const int row_base = q0 + w * 32;
#pragma unroll
        for (int rf = 0; rf < 2; ++rf)
#pragma unroll
            for (int c = 0; c < 4; ++c)
#pragma unroll
                for (int reg = 0; reg < 4; ++reg) {
                    float xx = s[rf][c][reg] * 0.125f + mval[c];
                    if (needMask) {
                        int rg = row_base + rf * 16 + hi * 4 + reg;
                        int cg = kv * 64 + c * 16 + lr;
                        if (cg > rg) xx = -1.0e30f;
                    }
                    s[rf][c][reg] = xx;
                }

        // online softmax
#pragma unroll
        for (int rf = 0; rf < 2; ++rf)
#pragma unroll
            for (int reg = 0; reg < 4; ++reg) {
                float tm = fmaxf(fmaxf(s[rf][0][reg], s[rf][1][reg]),
                                 fmaxf(s[rf][2][reg], s[rf][3][reg]));
#pragma unroll
                for (int d = 1; d < 16; d <<= 1) tm = fmaxf(tm, __shfl_xor(tm, d, 64));
                float mn = fmaxf(mrun[rf][reg], tm);
                float corr = __expf(mrun[rf][reg] - mn);
                mrun[rf][reg] = mn;
                float ps = 0.0f;
#pragma unroll
                for (int c = 0; c < 4; ++c) {
                    float p = __expf(s[rf][c][reg] - mn);
                    s[rf][c][reg] = p;
                    ps += p;
                }
#pragma unroll
                for (int d = 1; d < 16; d <<= 1) ps += __shfl_xor(ps, d, 64);
                lrun[rf][reg] = lrun[rf][reg] * corr + ps;
#pragma unroll
                for (int cf = 0; cf < 4; ++cf) o[rf][cf][reg] *= corr;
            }

        // P -> LDS (bf16), re-fragment as A operand
#pragma unroll
        for (int rf = 0; rf < 2; ++rf)
#pragma unroll
            for (int c = 0; c < 4; ++c)
#pragma unroll
                for (int reg = 0; reg < 4; ++reg)
                    Ps[w][(rf * 16 + hi * 4 + reg) * LDP + c * 16 + lr] = f2b(s[rf][c][reg]);

        short8x pa[2][2], vb[4][2];
#pragma unroll
        for (int rf = 0; rf < 2; ++rf)
#pragma unroll
            for (int ks = 0; ks < 2; ++ks)
                pa[rf][ks] = *(const short8x*)&Ps[w][(rf * 16 + lr) * LDP + ks * 32 + hi * 8];
#pragma unroll
        for (int cf = 0; cf < 4; ++cf)
#pragma unroll
            for (int ks = 0; ks < 2; ++ks)
                vb[cf][ks] = *(const short8x*)&Vt[(cf * 16 + lr) * LDP + ks * 32 + hi * 8];
#pragma unroll
        for (int rf = 0; rf < 2; ++rf)
#pragma unroll
            for (int cf = 0; cf < 4; ++cf)
#pragma unroll
                for (int ks = 0; ks < 2; ++ks)
                    o[rf][cf] = __builtin_amdgcn_mfma_f32_16x16x32_bf16(
                        pa[rf][ks], vb[cf][ks], o[rf][cf], 0, 0, 0);
    }

    // epilogue: normalize + write [B,T,H*D]
#pragma unroll
    for (int rf = 0; rf < 2; ++rf)
#pragma unroll
        for (int cf = 0; cf < 4; ++cf)
#pragma unroll
            for (int reg = 0; reg < 4; ++reg) {
                int t = q0 + w * 32 + rf * 16 + hi * 4 + reg;
                int d = cf * 16 + lr;
                out[((size_t)b * T_SEQ + t) * HID_SZ + h * HD + d] =
                    o[rf][cf][reg] / lrun[rf][reg];
            }
}

extern "C" void kernel_launch(void* const* d_in, const int* in_sizes, int n_in,
                              void* d_out, int out_size, void* d_ws, size_t ws_size,
                              hipStream_t stream) {
    const float* X    = (const float*)d_in[0];
    const float* mask = (const float*)d_in[1];
    const float* Wq   = (const float*)d_in[2];
    const float* bq   = (const float*)d_in[3];
    const float* Wk   = (const float*)d_in[4];
    const float* bk   = (const float*)d_in[5];
    const float* Wv   = (const float*)d_in[6];
    const float* bv   = (const float*)d_in[7];
    float* out = (float*)d_out;

    unsigned short* qw = (unsigned short*)d_ws;
    unsigned short* kw = qw + (size_t)B_SZ * T_SEQ * HID_SZ;
    unsigned short* vw = kw + (size_t)B_SZ * T_SEQ * HID_SZ;

    dim3 blk(256);
    dim3 gg(64, 6);
    qkv_gemm<<<gg, blk, 0, stream>>>(X, Wq, bq, qw);
    qkv_gemm<<<gg, blk, 0, stream>>>(X, Wk, bk, kw);
    qkv_gemm<<<gg, blk, 0, stream>>>(X, Wv, bv, vw);
    attn<<<dim3(16, 48), blk, 0, stream>>>(qw, kw, vw, mask, out);
}

// Round 8
// 290.816 us; speedup vs baseline: 1.2005x; 1.2005x over previous
//
#include <hip/hip_runtime.h>
#include <stdint.h>

typedef __attribute__((ext_vector_type(8))) short short8x;
typedef __attribute__((ext_vector_type(4))) float float4x;

#define B_SZ 4
#define T_SEQ 2048
#define HID_SZ 768
#define NH 12
#define HD 64
#define LDP 72   // padded LDS leading dim
#define QBLK 64
#define NT 32    // T_SEQ / QBLK

__device__ __forceinline__ unsigned short f2b(float f) {
    union { float f; unsigned int u; } v; v.f = f;
    unsigned int u = v.u;
    u += 0x7fffu + ((u >> 16) & 1u);   // RNE
    return (unsigned short)(u >> 16);
}

// ---------------- Fused QKV projection: z selects Q/K/V -------------------
__global__ __launch_bounds__(256) void qkv_gemm(
    const float* __restrict__ X,
    const float* __restrict__ Wq, const float* __restrict__ bq,
    const float* __restrict__ Wk, const float* __restrict__ bk,
    const float* __restrict__ Wv, const float* __restrict__ bv,
    unsigned short* __restrict__ Yq, unsigned short* __restrict__ Yk,
    unsigned short* __restrict__ Yv)
{
    const int z = blockIdx.z;
    const float* W    = (z == 0) ? Wq : (z == 1) ? Wk : Wv;
    const float* bias = (z == 0) ? bq : (z == 1) ? bk : bv;
    unsigned short* Y = (z == 0) ? Yq : (z == 1) ? Yk : Yv;

    __shared__ unsigned short As[128 * LDP];
    __shared__ unsigned short Bs[128 * LDP];
    const int tid  = threadIdx.x;
    const int lane = tid & 63;
    const int w    = tid >> 6;
    const int bm = blockIdx.x, bn = blockIdx.y;
    const int wm = (w >> 1) * 64, wn = (w & 1) * 64;
    const int lr = lane & 15;
    const int hi = lane >> 4;

    float4x acc[4][4];
#pragma unroll
    for (int i = 0; i < 4; ++i)
#pragma unroll
        for (int j = 0; j < 4; ++j) acc[i][j] = (float4x)0.0f;

    for (int k0 = 0; k0 < HID_SZ; k0 += 64) {
        __syncthreads();
#pragma unroll
        for (int i = 0; i < 8; ++i) {
            int f4 = tid + i * 256;          // 2048 float4 = 128 rows x 16
            int row = f4 >> 4, c4 = f4 & 15;
            float4 va = *(const float4*)(X + (size_t)(bm * 128 + row) * HID_SZ + k0 + c4 * 4);
            unsigned short* da = &As[row * LDP + c4 * 4];
            da[0] = f2b(va.x); da[1] = f2b(va.y); da[2] = f2b(va.z); da[3] = f2b(va.w);
            float4 vb = *(const float4*)(W + (size_t)(bn * 128 + row) * HID_SZ + k0 + c4 * 4);
            unsigned short* db = &Bs[row * LDP + c4 * 4];
            db[0] = f2b(vb.x); db[1] = f2b(vb.y); db[2] = f2b(vb.z); db[3] = f2b(vb.w);
        }
        __syncthreads();

        short8x a[4][2], bf[4][2];
#pragma unroll
        for (int rf = 0; rf < 4; ++rf)
#pragma unroll
            for (int ks = 0; ks < 2; ++ks)
                a[rf][ks] = *(const short8x*)&As[(wm + rf * 16 + lr) * LDP + ks * 32 + hi * 8];
#pragma unroll
        for (int cf = 0; cf < 4; ++cf)
#pragma unroll
            for (int ks = 0; ks < 2; ++ks)
                bf[cf][ks] = *(const short8x*)&Bs[(wn + cf * 16 + lr) * LDP + ks * 32 + hi * 8];
#pragma unroll
        for (int rf = 0; rf < 4; ++rf)
#pragma unroll
            for (int cf = 0; cf < 4; ++cf)
#pragma unroll
                for (int ks = 0; ks < 2; ++ks)
                    acc[rf][cf] = __builtin_amdgcn_mfma_f32_16x16x32_bf16(
                        a[rf][ks], bf[cf][ks], acc[rf][cf], 0, 0, 0);
    }

#pragma unroll
    for (int rf = 0; rf < 4; ++rf)
#pragma unroll
        for (int cf = 0; cf < 4; ++cf) {
            int n = bn * 128 + wn + cf * 16 + lr;
            float bv = bias[n];
            int h = n >> 6, d = n & 63;
#pragma unroll
            for (int reg = 0; reg < 4; ++reg) {
                int m = bm * 128 + wm + rf * 16 + hi * 4 + reg;
                int b = m >> 11, t = m & 2047;
                Y[(((size_t)b * NH + h) * T_SEQ + t) * HD + d] = f2b(acc[rf][cf][reg] + bv);
            }
        }
}

// ---------------- Flash attention: paired causal tiles, balanced ----------
// Block (bx, bh): processes q-tiles jj=bx and jj=NT-1-bx  -> 33 KV iters each.
// Q,K fragments direct from global; V double-buffered in LDS (XOR swizzle).
__global__ __launch_bounds__(256) void attn(
    const unsigned short* __restrict__ Q, const unsigned short* __restrict__ K,
    const unsigned short* __restrict__ V, const float* __restrict__ mask,
    float* __restrict__ out)
{
    __shared__ unsigned short Vt[2][HD * LDP];  // [d][key ^ swz], double-buffered
    __shared__ unsigned short Ps[4][16 * LDP];  // per-wave P transpose buffer

    const int tid = threadIdx.x, lane = tid & 63, w = tid >> 6;
    const int lr = lane & 15, hi = lane >> 4;
    const int bx = blockIdx.x;            // 0..15 pair index
    const int bh = blockIdx.y;            // b*NH + h
    const int b = bh / NH, h = bh % NH;
    const size_t base = (size_t)bh * T_SEQ * HD;

    // V staging coords: each thread handles rows r0,r1 x 8 d's (c8*8..+7)
    const int c8 = tid & 7;
    const int r0 = tid >> 3;              // 0..31
    const int r1 = r0 + 32;               // 32..63
    const int pr0 = r0 ^ (c8 << 3);       // swizzled key column
    const int pr1 = r1 ^ (c8 << 3);

    for (int pass = 0; pass < 2; ++pass) {
        const int jj = pass ? (NT - 1 - bx) : bx;
        const int q0 = jj * QBLK;

        // Q fragments direct from global (loop-invariant per pass)
        short8x qa[2];
#pragma unroll
        for (int ks = 0; ks < 2; ++ks)
            qa[ks] = *(const short8x*)(Q + base + (size_t)(q0 + w * 16 + lr) * HD + ks * 32 + hi * 8);

        float4x o[4];
        float mrun[4], lrun[4];
#pragma unroll
        for (int j = 0; j < 4; ++j) {
            o[j] = (float4x)0.0f;
            mrun[j] = -3.0e38f;
            lrun[j] = 0.0f;
        }

        __syncthreads();   // previous pass readers done before Vt[0] rewrite
        {   // stage V tile 0
            short8x v0 = *(const short8x*)(V + base + (size_t)r0 * HD + c8 * 8);
            short8x v1 = *(const short8x*)(V + base + (size_t)r1 * HD + c8 * 8);
#pragma unroll
            for (int j = 0; j < 8; ++j) {
                Vt[0][(c8 * 8 + j) * LDP + pr0] = (unsigned short)v0[j];
                Vt[0][(c8 * 8 + j) * LDP + pr1] = (unsigned short)v1[j];
            }
        }
        __syncthreads();

        int cur = 0;
        for (int kv = 0; kv <= jj; ++kv) {
            const bool pf = (kv < jj);
            short8x nv0, nv1;
            if (pf) {   // prefetch next V tile into regs (latency hidden under compute)
                nv0 = *(const short8x*)(V + base + (size_t)((kv + 1) * 64 + r0) * HD + c8 * 8);
                nv1 = *(const short8x*)(V + base + (size_t)((kv + 1) * 64 + r1) * HD + c8 * 8);
            }

            // K fragments direct from global (L1/L2-hot: 4 waves share tile)
            short8x kb[4][2];
#pragma unroll
            for (int c = 0; c < 4; ++c)
#pragma unroll
                for (int ks = 0; ks < 2; ++ks)
                    kb[c][ks] = *(const short8x*)(K + base + (size_t)(kv * 64 + c * 16 + lr) * HD + ks * 32 + hi * 8);

            // S = Q K^T (wave: 16 q-rows x 64 keys)
            float4x s[4];
#pragma unroll
            for (int c = 0; c < 4; ++c) {
                s[c] = (float4x)0.0f;
#pragma unroll
                for (int ks = 0; ks < 2; ++ks)
                    s[c] = __builtin_amdgcn_mfma_f32_16x16x32_bf16(
                        qa[ks], kb[c][ks], s[c], 0, 0, 0);
            }

            // scale + additive mask + causal (diagonal tile only)
            float mval[4];
#pragma unroll
            for (int c = 0; c < 4; ++c) mval[c] = mask[b * T_SEQ + kv * 64 + c * 16 + lr];
            const bool diag = (kv == jj);
#pragma unroll
            for (int c = 0; c < 4; ++c)
#pragma unroll
                for (int reg = 0; reg < 4; ++reg) {
                    float xx = s[c][reg] * 0.125f + mval[c];
                    if (diag) {
                        int rg = w * 16 + hi * 4 + reg;   // row within tile
                        int cg = c * 16 + lr;             // col within tile
                        if (cg > rg) xx = -1.0e30f;
                    }
                    s[c][reg] = xx;
                }

            // online softmax (row-reduce over 16 lr lanes)
#pragma unroll
            for (int reg = 0; reg < 4; ++reg) {
                float tm = fmaxf(fmaxf(s[0][reg], s[1][reg]),
                                 fmaxf(s[2][reg], s[3][reg]));
#pragma unroll
                for (int d = 1; d < 16; d <<= 1) tm = fmaxf(tm, __shfl_xor(tm, d, 64));
                float mn = fmaxf(mrun[reg], tm);
                float corr = __expf(mrun[reg] - mn);
                mrun[reg] = mn;
                float ps = 0.0f;
#pragma unroll
                for (int c = 0; c < 4; ++c) {
                    float p = __expf(s[c][reg] - mn);
                    s[c][reg] = p;
                    ps += p;
                }
#pragma unroll
                for (int d = 1; d < 16; d <<= 1) ps += __shfl_xor(ps, d, 64);
                lrun[reg] = lrun[reg] * corr + ps;
#pragma unroll
                for (int cf = 0; cf < 4; ++cf) o[cf][reg] *= corr;
            }

            // P -> per-wave LDS (transpose to A-fragment layout)
#pragma unroll
            for (int c = 0; c < 4; ++c)
#pragma unroll
                for (int reg = 0; reg < 4; ++reg)
                    Ps[w][(hi * 4 + reg) * LDP + c * 16 + lr] = f2b(s[c][reg]);

            short8x pa[2], vb[4][2];
#pragma unroll
            for (int ks = 0; ks < 2; ++ks)
                pa[ks] = *(const short8x*)&Ps[w][lr * LDP + ks * 32 + hi * 8];
#pragma unroll
            for (int cf = 0; cf < 4; ++cf)
#pragma unroll
                for (int ks = 0; ks < 2; ++ks) {
                    int d = cf * 16 + lr;
                    int pcb = (ks * 32 + hi * 8) ^ (((d >> 3) & 7) << 3);
                    vb[cf][ks] = *(const short8x*)&Vt[cur][d * LDP + pcb];
                }
#pragma unroll
            for (int cf = 0; cf < 4; ++cf)
#pragma unroll
                for (int ks = 0; ks < 2; ++ks)
                    o[cf] = __builtin_amdgcn_mfma_f32_16x16x32_bf16(
                        pa[ks], vb[cf][ks], o[cf], 0, 0, 0);

            if (pf) {   // write prefetched V to the other buffer; 1 barrier/iter
                int nxt = cur ^ 1;
#pragma unroll
                for (int j = 0; j < 8; ++j) {
                    Vt[nxt][(c8 * 8 + j) * LDP + pr0] = (unsigned short)nv0[j];
                    Vt[nxt][(c8 * 8 + j) * LDP + pr1] = (unsigned short)nv1[j];
                }
                __syncthreads();
                cur = nxt;
            }
        }

        // epilogue: normalize + write [B,T,H*D]
#pragma unroll
        for (int cf = 0; cf < 4; ++cf)
#pragma unroll
            for (int reg = 0; reg < 4; ++reg) {
                int t = q0 + w * 16 + hi * 4 + reg;
                int d = cf * 16 + lr;
                out[((size_t)b * T_SEQ + t) * HID_SZ + h * HD + d] =
                    o[cf][reg] / lrun[reg];
            }
    }
}

extern "C" void kernel_launch(void* const* d_in, const int* in_sizes, int n_in,
                              void* d_out, int out_size, void* d_ws, size_t ws_size,
                              hipStream_t stream) {
    const float* X    = (const float*)d_in[0];
    const float* mask = (const float*)d_in[1];
    const float* Wq   = (const float*)d_in[2];
    const float* bq   = (const float*)d_in[3];
    const float* Wk   = (const float*)d_in[4];
    const float* bk   = (const float*)d_in[5];
    const float* Wv   = (const float*)d_in[6];
    const float* bv   = (const float*)d_in[7];
    float* out = (float*)d_out;

    unsigned short* qw = (unsigned short*)d_ws;
    unsigned short* kw = qw + (size_t)B_SZ * T_SEQ * HID_SZ;
    unsigned short* vw = kw + (size_t)B_SZ * T_SEQ * HID_SZ;

    dim3 blk(256);
    qkv_gemm<<<dim3(64, 6, 3), blk, 0, stream>>>(X, Wq, bq, Wk, bk, Wv, bv, qw, kw, vw);
    attn<<<dim3(16, 48), blk, 0, stream>>>(qw, kw, vw, mask, out);
}

// Round 11
// 217.068 us; speedup vs baseline: 1.6084x; 1.3397x over previous
//
#include <hip/hip_runtime.h>
#include <stdint.h>

typedef __attribute__((ext_vector_type(8))) short short8x;
typedef __attribute__((ext_vector_type(4))) float float4x;
typedef __attribute__((ext_vector_type(4))) unsigned short ushort4x;

#define B_SZ 4
#define T_SEQ 2048
#define HID_SZ 768
#define NH 12
#define HD 64
#define LDP 72   // padded LDS leading dim
#define QBLK 64
#define NT 32    // T_SEQ / QBLK

__device__ __forceinline__ unsigned short f2b(float f) {
    union { float f; unsigned int u; } v; v.f = f;
    unsigned int u = v.u;
    u += 0x7fffu + ((u >> 16) & 1u);   // RNE
    return (unsigned short)(u >> 16);
}

// ---------------- Fused QKV projection: z selects Q/K/V -------------------
__global__ __launch_bounds__(256) void qkv_gemm(
    const float* __restrict__ X,
    const float* __restrict__ Wq, const float* __restrict__ bq,
    const float* __restrict__ Wk, const float* __restrict__ bk,
    const float* __restrict__ Wv, const float* __restrict__ bv,
    unsigned short* __restrict__ Yq, unsigned short* __restrict__ Yk,
    unsigned short* __restrict__ Yv)
{
    const int z = blockIdx.z;
    const float* W    = (z == 0) ? Wq : (z == 1) ? Wk : Wv;
    const float* bias = (z == 0) ? bq : (z == 1) ? bk : bv;
    unsigned short* Y = (z == 0) ? Yq : (z == 1) ? Yk : Yv;

    __shared__ unsigned short As[128 * LDP];
    __shared__ unsigned short Bs[128 * LDP];
    const int tid  = threadIdx.x;
    const int lane = tid & 63;
    const int w    = tid >> 6;
    const int bm = blockIdx.x, bn = blockIdx.y;
    const int wm = (w >> 1) * 64, wn = (w & 1) * 64;
    const int lr = lane & 15;
    const int hi = lane >> 4;

    float4x acc[4][4];
#pragma unroll
    for (int i = 0; i < 4; ++i)
#pragma unroll
        for (int j = 0; j < 4; ++j) acc[i][j] = (float4x)0.0f;

    for (int k0 = 0; k0 < HID_SZ; k0 += 64) {
        __syncthreads();
#pragma unroll
        for (int i = 0; i < 8; ++i) {
            int f4 = tid + i * 256;          // 2048 float4 = 128 rows x 16
            int row = f4 >> 4, c4 = f4 & 15;
            float4 va = *(const float4*)(X + (size_t)(bm * 128 + row) * HID_SZ + k0 + c4 * 4);
            unsigned short* da = &As[row * LDP + c4 * 4];
            da[0] = f2b(va.x); da[1] = f2b(va.y); da[2] = f2b(va.z); da[3] = f2b(va.w);
            float4 vb = *(const float4*)(W + (size_t)(bn * 128 + row) * HID_SZ + k0 + c4 * 4);
            unsigned short* db = &Bs[row * LDP + c4 * 4];
            db[0] = f2b(vb.x); db[1] = f2b(vb.y); db[2] = f2b(vb.z); db[3] = f2b(vb.w);
        }
        __syncthreads();

        short8x a[4][2], bf[4][2];
#pragma unroll
        for (int rf = 0; rf < 4; ++rf)
#pragma unroll
            for (int ks = 0; ks < 2; ++ks)
                a[rf][ks] = *(const short8x*)&As[(wm + rf * 16 + lr) * LDP + ks * 32 + hi * 8];
#pragma unroll
        for (int cf = 0; cf < 4; ++cf)
#pragma unroll
            for (int ks = 0; ks < 2; ++ks)
                bf[cf][ks] = *(const short8x*)&Bs[(wn + cf * 16 + lr) * LDP + ks * 32 + hi * 8];
#pragma unroll
        for (int rf = 0; rf < 4; ++rf)
#pragma unroll
            for (int cf = 0; cf < 4; ++cf)
#pragma unroll
                for (int ks = 0; ks < 2; ++ks)
                    acc[rf][cf] = __builtin_amdgcn_mfma_f32_16x16x32_bf16(
                        a[rf][ks], bf[cf][ks], acc[rf][cf], 0, 0, 0);
    }

#pragma unroll
    for (int rf = 0; rf < 4; ++rf)
#pragma unroll
        for (int cf = 0; cf < 4; ++cf) {
            int n = bn * 128 + wn + cf * 16 + lr;
            float bv = bias[n];
            int h = n >> 6, d = n & 63;
#pragma unroll
            for (int reg = 0; reg < 4; ++reg) {
                int m = bm * 128 + wm + rf * 16 + hi * 4 + reg;
                int b = m >> 11, t = m & 2047;
                Y[(((size_t)b * NH + h) * T_SEQ + t) * HD + d] = f2b(acc[rf][cf][reg] + bv);
            }
        }
}

// ---------------- Flash attention: swapped-operand, paired causal tiles ----
// S^T = mfma(K,Q): lane owns one q-row -> in-lane softmax (2 shfl per reduce).
// o^T = mfma(V^T, P): corr/lrun lane-local; float4 epilogue.
// K double-buffered in regs (two-body loop); V double-buffered in LDS.
__global__ __launch_bounds__(256) void attn(
    const unsigned short* __restrict__ Q, const unsigned short* __restrict__ K,
    const unsigned short* __restrict__ V, const float* __restrict__ mask,
    float* __restrict__ out)
{
    __shared__ unsigned short Vt[2][HD * LDP];  // [d][key ^ swz], double-buffered
    __shared__ unsigned short Ps[4][16 * LDP];  // per-wave P: [q][key]
    __shared__ float Ms[T_SEQ];                 // mask row for this b

    const int tid = threadIdx.x, lane = tid & 63, w = tid >> 6;
    const int lr = lane & 15, hi = lane >> 4;
    const int bx = blockIdx.x;            // 0..15 pair index
    const int bh = blockIdx.y;            // b*NH + h
    const int b = bh / NH, h = bh % NH;
    const size_t base = (size_t)bh * T_SEQ * HD;

    // stage mask row once (read-only afterwards)
    {
        int t8 = tid * 8;
        *(float4*)&Ms[t8]     = *(const float4*)&mask[b * T_SEQ + t8];
        *(float4*)&Ms[t8 + 4] = *(const float4*)&mask[b * T_SEQ + t8 + 4];
    }

    // V staging coords: each thread handles rows r0,r1 x 8 d's (c8*8..+7)
    const int c8 = tid & 7;
    const int r0 = tid >> 3;              // 0..31
    const int r1 = r0 + 32;               // 32..63
    const int pr0 = r0 ^ (c8 << 3);       // swizzled key column
    const int pr1 = r1 ^ (c8 << 3);

    for (int pass = 0; pass < 2; ++pass) {
        const int jj = pass ? (NT - 1 - bx) : bx;
        const int q0 = jj * QBLK;

        // Q fragments direct from global (B-operand; loop-invariant per pass)
        short8x qa[2];
#pragma unroll
        for (int ks = 0; ks < 2; ++ks)
            qa[ks] = *(const short8x*)(Q + base + (size_t)(q0 + w * 16 + lr) * HD + ks * 32 + hi * 8);

        float4x o[4];
        float mrun = -3.0e38f, lrun = 0.0f;
#pragma unroll
        for (int j = 0; j < 4; ++j) o[j] = (float4x)0.0f;

        __syncthreads();   // previous pass readers done before Vt[0] rewrite
        {   // stage V tile 0
            short8x v0 = *(const short8x*)(V + base + (size_t)r0 * HD + c8 * 8);
            short8x v1 = *(const short8x*)(V + base + (size_t)r1 * HD + c8 * 8);
#pragma unroll
            for (int j = 0; j < 8; ++j) {
                Vt[0][(c8 * 8 + j) * LDP + pr0] = (unsigned short)v0[j];
                Vt[0][(c8 * 8 + j) * LDP + pr1] = (unsigned short)v1[j];
            }
        }
        __syncthreads();

        int cur = 0;
        int kv = 0;
        short8x kb0[4][2], kb1[4][2];
#pragma unroll
        for (int c = 0; c < 4; ++c)
#pragma unroll
            for (int ks = 0; ks < 2; ++ks)
                kb0[c][ks] = *(const short8x*)(K + base + (size_t)(c * 16 + lr) * HD + ks * 32 + hi * 8);

        // one iteration body; kb = current K frags, kbn = prefetch target
        auto body = [&](short8x (&kb)[4][2], short8x (&kbn)[4][2]) -> bool {
            const bool pf = (kv < jj);
            short8x nv0, nv1;
            if (pf) {   // prefetch next K (regs) and next V (regs->LDS later)
#pragma unroll
                for (int c = 0; c < 4; ++c)
#pragma unroll
                    for (int ks = 0; ks < 2; ++ks)
                        kbn[c][ks] = *(const short8x*)(K + base + (size_t)((kv + 1) * 64 + c * 16 + lr) * HD + ks * 32 + hi * 8);
                nv0 = *(const short8x*)(V + base + (size_t)((kv + 1) * 64 + r0) * HD + c8 * 8);
                nv1 = *(const short8x*)(V + base + (size_t)((kv + 1) * 64 + r1) * HD + c8 * 8);
            }

            // S^T = K Q^T : s[c] = keys c*16..+15 x q (lane owns q = lr)
            float4x s[4];
#pragma unroll
            for (int c = 0; c < 4; ++c) {
                s[c] = (float4x)0.0f;
#pragma unroll
                for (int ks = 0; ks < 2; ++ks)
                    s[c] = __builtin_amdgcn_mfma_f32_16x16x32_bf16(
                        kb[c][ks], qa[ks], s[c], 0, 0, 0);
            }

            // scale + additive mask (LDS) + causal (diag tile only)
            const bool diag = (kv == jj);
            const int qloc = w * 16 + lr;
#pragma unroll
            for (int c = 0; c < 4; ++c) {
                float4 mv = *(const float4*)&Ms[kv * 64 + c * 16 + hi * 4];
#pragma unroll
                for (int reg = 0; reg < 4; ++reg) {
                    float x = s[c][reg] * 0.125f + ((const float*)&mv)[reg];
                    if (diag) {
                        int kloc = c * 16 + hi * 4 + reg;
                        if (kloc > qloc) x = -1.0e30f;
                    }
                    s[c][reg] = x;
                }
            }

            // in-lane online softmax (q = lr): 16 values in-lane + hi-lanes
            float tm = -3.0e38f;
#pragma unroll
            for (int c = 0; c < 4; ++c)
#pragma unroll
                for (int reg = 0; reg < 4; ++reg) tm = fmaxf(tm, s[c][reg]);
            tm = fmaxf(tm, __shfl_xor(tm, 16, 64));
            tm = fmaxf(tm, __shfl_xor(tm, 32, 64));
            float mn = fmaxf(mrun, tm);
            float corr = __expf(mrun - mn);
            mrun = mn;
            float ps = 0.0f;
#pragma unroll
            for (int c = 0; c < 4; ++c)
#pragma unroll
                for (int reg = 0; reg < 4; ++reg) {
                    float p = __expf(s[c][reg] - mn);
                    s[c][reg] = p;
                    ps += p;
                }
            ps += __shfl_xor(ps, 16, 64);
            ps += __shfl_xor(ps, 32, 64);
            lrun = lrun * corr + ps;
#pragma unroll
            for (int cf = 0; cf < 4; ++cf) o[cf] *= corr;

            // P -> Ps[q][key]: 4 regs are key-consecutive -> packed b64 writes
#pragma unroll
            for (int c = 0; c < 4; ++c) {
                ushort4x pk;
                pk.x = f2b(s[c][0]); pk.y = f2b(s[c][1]);
                pk.z = f2b(s[c][2]); pk.w = f2b(s[c][3]);
                *(ushort4x*)&Ps[w][lr * LDP + c * 16 + hi * 4] = pk;
            }

            short8x pa[2], vb[4][2];
#pragma unroll
            for (int ks = 0; ks < 2; ++ks)
                pa[ks] = *(const short8x*)&Ps[w][lr * LDP + ks * 32 + hi * 8];
#pragma unroll
            for (int cf = 0; cf < 4; ++cf)
#pragma unroll
                for (int ks = 0; ks < 2; ++ks) {
                    int d = cf * 16 + lr;
                    int pcb = (ks * 32 + hi * 8) ^ (((d >> 3) & 7) << 3);
                    vb[cf][ks] = *(const short8x*)&Vt[cur][d * LDP + pcb];
                }
            // o^T += V^T P : col = q (lane-local), row = d-within-tile
#pragma unroll
            for (int cf = 0; cf < 4; ++cf)
#pragma unroll
                for (int ks = 0; ks < 2; ++ks)
                    o[cf] = __builtin_amdgcn_mfma_f32_16x16x32_bf16(
                        vb[cf][ks], pa[ks], o[cf], 0, 0, 0);

            if (pf) {   // write prefetched V to the other buffer; 1 barrier/iter
                int nxt = cur ^ 1;
#pragma unroll
                for (int j = 0; j < 8; ++j) {
                    Vt[nxt][(c8 * 8 + j) * LDP + pr0] = (unsigned short)nv0[j];
                    Vt[nxt][(c8 * 8 + j) * LDP + pr1] = (unsigned short)nv1[j];
                }
                __syncthreads();
                cur = nxt;
            }
            ++kv;
            return pf;
        };

        while (true) {
            if (!body(kb0, kb1)) break;   // uses kb0, prefetches kb1
            if (!body(kb1, kb0)) break;   // uses kb1, prefetches kb0
        }

        // epilogue: normalize + write [B,T,H*D]; lane owns row t, 16 d's
        float inv = 1.0f / lrun;
        int t = q0 + w * 16 + lr;
#pragma unroll
        for (int cf = 0; cf < 4; ++cf) {
            float4 st;
            st.x = o[cf][0] * inv; st.y = o[cf][1] * inv;
            st.z = o[cf][2] * inv; st.w = o[cf][3] * inv;
            *(float4*)(out + ((size_t)b * T_SEQ + t) * HID_SZ + h * HD + cf * 16 + hi * 4) = st;
        }
    }
}

extern "C" void kernel_launch(void* const* d_in, const int* in_sizes, int n_in,
                              void* d_out, int out_size, void* d_ws, size_t ws_size,
                              hipStream_t stream) {
    const float* X    = (const float*)d_in[0];
    const float* mask = (const float*)d_in[1];
    const float* Wq   = (const float*)d_in[2];
    const float* bq   = (const float*)d_in[3];
    const float* Wk   = (const float*)d_in[4];
    const float* bk   = (const float*)d_in[5];
    const float* Wv   = (const float*)d_in[6];
    const float* bv   = (const float*)d_in[7];
    float* out = (float*)d_out;

    unsigned short* qw = (unsigned short*)d_ws;
    unsigned short* kw = qw + (size_t)B_SZ * T_SEQ * HID_SZ;
    unsigned short* vw = kw + (size_t)B_SZ * T_SEQ * HID_SZ;

    dim3 blk(256);
    qkv_gemm<<<dim3(64, 6, 3), blk, 0, stream>>>(X, Wq, bq, Wk, bk, Wv, bv, qw, kw, vw);
    attn<<<dim3(16, 48), blk, 0, stream>>>(qw, kw, vw, mask, out);
}